// Round 3
// baseline (429.596 us; speedup 1.0000x reference)
//
#include <hip/hip_runtime.h>

#define D_FEAT 64
#define NEG_INF_BITS 0xFF800000u
#define ENC_NEG_INF  0x007FFFFFu   // order-preserving encoding of -inf
#define NPB 128                     // nodes per bucket (= 1 << BSHIFT)
#define BSHIFT 7
#define TILE_T 16                   // edges per thread in scatter pass
#define TILE_E (256 * TILE_T)       // 4096 edges per tile
#define MAXB 1024                   // max buckets (scan block size)

// Order-preserving float->uint: enc monotone increasing with float value.
__device__ __forceinline__ unsigned enc_f32(float v) {
    unsigned b = __float_as_uint(v);
    return ((int)b >= 0) ? (b ^ 0x80000000u) : ~b;
}
__device__ __forceinline__ float dec_f32(unsigned u) {
    return (u & 0x80000000u) ? __uint_as_float(u ^ 0x80000000u) : __uint_as_float(~u);
}

// ---------- phase 0: zero histogram ----------
__global__ void zero_kernel(int* __restrict__ p, int n) {
    int i = blockIdx.x * blockDim.x + threadIdx.x;
    if (i < n) p[i] = 0;
}

// ---------- phase 1a: bucket histogram (LDS-privatized) ----------
__global__ void hist_kernel(const int* __restrict__ dst, int* __restrict__ hist,
                            int E, int B) {
    __shared__ int lh[MAXB];
    for (int i = threadIdx.x; i < B; i += blockDim.x) lh[i] = 0;
    __syncthreads();
    for (int i = blockIdx.x * blockDim.x + threadIdx.x; i < E;
         i += gridDim.x * blockDim.x) {
        atomicAdd(&lh[dst[i] >> BSHIFT], 1);
    }
    __syncthreads();
    for (int i = threadIdx.x; i < B; i += blockDim.x) {
        int c = lh[i];
        if (c) atomicAdd(&hist[i], c);
    }
}

// ---------- phase 1b: exclusive scan (single block) ----------
// bucket_start[0..B] (immutable starts, start[B]=E), cursor[0..B) (advancing).
__global__ void scan_kernel(const int* __restrict__ hist, int* __restrict__ bucket_start,
                            int* __restrict__ cursor, int B) {
    __shared__ int lds[MAXB];
    int tid = threadIdx.x;
    int v = (tid < B) ? hist[tid] : 0;
    lds[tid] = v;
    __syncthreads();
    for (int off = 1; off < MAXB; off <<= 1) {
        int t = (tid >= off) ? lds[tid - off] : 0;
        __syncthreads();
        lds[tid] += t;
        __syncthreads();
    }
    if (tid < B) {
        int excl = lds[tid] - v;
        bucket_start[tid] = excl;
        cursor[tid] = excl;
        if (tid == B - 1) bucket_start[B] = lds[tid];
    }
}

// ---------- phase 1c: block-chunked scatter into buckets ----------
// Each block handles one TILE_E-edge tile. Two LDS passes: count per bucket,
// reserve a contiguous global chunk per bucket (1 atomic per (block,bucket)),
// then place edges via LDS atomics. Packed edge: src | (local_dst << 17).
__global__ void scatter_pass_kernel(const int* __restrict__ src, const int* __restrict__ dst,
                                    int* __restrict__ cursor, unsigned* __restrict__ packed,
                                    int E, int B) {
    __shared__ int lcount[MAXB];
    __shared__ int lbase[MAXB];
    int tid = threadIdx.x;
    int base = blockIdx.x * TILE_E;

    for (int i = tid; i < B; i += 256) lcount[i] = 0;
    __syncthreads();

    // pass 1: count
    for (int k = 0; k < TILE_T; ++k) {
        int i = base + k * 256 + tid;
        if (i < E) atomicAdd(&lcount[dst[i] >> BSHIFT], 1);
    }
    __syncthreads();

    // reserve global chunks, reset counters
    for (int b = tid; b < B; b += 256) {
        int c = lcount[b];
        lbase[b] = c ? atomicAdd(&cursor[b], c) : 0;
        lcount[b] = 0;
    }
    __syncthreads();

    // pass 2: place
    for (int k = 0; k < TILE_T; ++k) {
        int i = base + k * 256 + tid;
        if (i < E) {
            int d = dst[i];
            int b = d >> BSHIFT;
            int pos = lbase[b] + atomicAdd(&lcount[b], 1);
            packed[pos] = (unsigned)src[i] | ((unsigned)(d & (NPB - 1)) << 17);
        }
    }
}

// ---------- phase 2: per-bucket scatter-max in LDS ----------
__global__ void bucket_max_kernel(const float* __restrict__ h,
                                  const int* __restrict__ bucket_start,
                                  const unsigned* __restrict__ packed,
                                  float* __restrict__ out, int N) {
    __shared__ unsigned buf[NPB * D_FEAT];   // 32 KB
    int b = blockIdx.x;
    int tid = threadIdx.x;
    int node0 = b << BSHIFT;
    int nvals = (min(NPB, N - node0)) * D_FEAT;

    for (int i = tid; i < nvals; i += 256) buf[i] = ENC_NEG_INF;
    __syncthreads();

    int beg = bucket_start[b];
    int end = bucket_start[b + 1];
    int wave = tid >> 6;
    int lane = tid & 63;
    for (int e = beg + wave; e < end; e += 4) {
        unsigned p = packed[e];
        int s = (int)(p & 0x1FFFFu);
        int local = (int)(p >> 17);
        float v = h[s * D_FEAT + lane];
        atomicMax(&buf[local * D_FEAT + lane], enc_f32(v));
    }
    __syncthreads();

    for (int i = tid; i < nvals; i += 256) {
        unsigned u = buf[i];
        out[node0 * D_FEAT + i] = (u == ENC_NEG_INF) ? 0.0f : dec_f32(u);
    }
}

// ---------- fallback: atomic scatter (round-1 path) ----------
__global__ void init_out_kernel(uint4* __restrict__ out, int n4) {
    int i = blockIdx.x * blockDim.x + threadIdx.x;
    if (i < n4) {
        uint4 v;
        v.x = NEG_INF_BITS; v.y = NEG_INF_BITS; v.z = NEG_INF_BITS; v.w = NEG_INF_BITS;
        out[i] = v;
    }
}
__global__ void scatter_max_kernel(const float* __restrict__ h, const int* __restrict__ src,
                                   const int* __restrict__ dst, float* __restrict__ out, int E) {
    int gid = blockIdx.x * blockDim.x + threadIdx.x;
    int e = gid >> 6;
    if (e >= E) return;
    int lane = gid & 63;
    float v = h[src[e] * D_FEAT + lane];
    int* addr = (int*)(out + dst[e] * D_FEAT + lane);
    if (v >= 0.0f) atomicMax(addr, __float_as_int(v));
    else           atomicMin((unsigned int*)addr, __float_as_uint(v));
}
__global__ void finalize_kernel(float* __restrict__ out, int n) {
    int i = blockIdx.x * blockDim.x + threadIdx.x;
    if (i < n && __float_as_uint(out[i]) == NEG_INF_BITS) out[i] = 0.0f;
}

// ---------- launch ----------
extern "C" void kernel_launch(void* const* d_in, const int* in_sizes, int n_in,
                              void* d_out, int out_size, void* d_ws, size_t ws_size,
                              hipStream_t stream) {
    const float* h = (const float*)d_in[0];
    const int* edge_index = (const int*)d_in[1];
    int E = in_sizes[1] / 2;                 // edge_index is [2, E] row-major
    const int* src = edge_index;
    const int* dst = edge_index + E;
    float* out = (float*)d_out;
    int N = out_size / D_FEAT;

    int B = (N + NPB - 1) >> BSHIFT;
    size_t ws_needed = (size_t)(2 * B + 2 + E) * sizeof(int);

    if (N <= (1 << 17) && B <= MAXB && ws_size >= ws_needed) {
        int* hist         = (int*)d_ws;            // [B]
        int* bucket_start = hist + B;              // [B+1]
        int* cursor       = bucket_start + B + 1;  // [B]
        unsigned* packed  = (unsigned*)(cursor + B); // [E]

        zero_kernel<<<(B + 255) / 256, 256, 0, stream>>>(hist, B);
        hist_kernel<<<256, 256, 0, stream>>>(dst, hist, E, B);
        scan_kernel<<<1, MAXB, 0, stream>>>(hist, bucket_start, cursor, B);
        int ntiles = (E + TILE_E - 1) / TILE_E;
        scatter_pass_kernel<<<ntiles, 256, 0, stream>>>(src, dst, cursor, packed, E, B);
        bucket_max_kernel<<<B, 256, 0, stream>>>(h, bucket_start, packed, out, N);
    } else {
        int n4 = out_size / 4;
        init_out_kernel<<<(n4 + 255) / 256, 256, 0, stream>>>((uint4*)out, n4);
        long long total = (long long)E * 64;
        scatter_max_kernel<<<(int)((total + 255) / 256), 256, 0, stream>>>(h, src, dst, out, E);
        finalize_kernel<<<(out_size + 255) / 256, 256, 0, stream>>>(out, out_size);
    }
}

// Round 4
// 178.097 us; speedup vs baseline: 2.4122x; 2.4122x over previous
//
#include <hip/hip_runtime.h>

#define D_FEAT 64
#define NEG_INF_BITS 0xFF800000u
#define ENC_NEG_INF  0x007FFFFFu   // order-preserving encoding of -inf
#define NPB 128                     // nodes per bucket (= 1 << BSHIFT)
#define BSHIFT 7
#define TILE_E 4096                 // edges per scatter tile
#define SP_BLOCK 512                // scatter_pass threads
#define BM_BLOCK 512                // bucket_max threads (8 waves)
#define MAXB 1024                   // max buckets (scan block size)

// Order-preserving float->uint: enc monotone increasing with float value.
__device__ __forceinline__ unsigned enc_f32(float v) {
    unsigned b = __float_as_uint(v);
    return ((int)b >= 0) ? (b ^ 0x80000000u) : ~b;
}
__device__ __forceinline__ float dec_f32(unsigned u) {
    return (u & 0x80000000u) ? __uint_as_float(u ^ 0x80000000u) : __uint_as_float(~u);
}

__global__ void zero_kernel(int* __restrict__ p, int n) {
    int i = blockIdx.x * blockDim.x + threadIdx.x;
    if (i < n) p[i] = 0;
}

// ---------- phase 1a: bucket histogram (LDS-privatized, int4 loads) ----------
__global__ void hist_kernel(const int* __restrict__ dst, int* __restrict__ hist,
                            int E, int B) {
    __shared__ int lh[MAXB];
    for (int i = threadIdx.x; i < B; i += blockDim.x) lh[i] = 0;
    __syncthreads();
    int E4 = E >> 2;
    const int4* dst4 = (const int4*)dst;
    for (int i = blockIdx.x * blockDim.x + threadIdx.x; i < E4;
         i += gridDim.x * blockDim.x) {
        int4 d = dst4[i];
        atomicAdd(&lh[d.x >> BSHIFT], 1);
        atomicAdd(&lh[d.y >> BSHIFT], 1);
        atomicAdd(&lh[d.z >> BSHIFT], 1);
        atomicAdd(&lh[d.w >> BSHIFT], 1);
    }
    // tail
    if (blockIdx.x == 0) {
        for (int i = (E4 << 2) + threadIdx.x; i < E; i += blockDim.x)
            atomicAdd(&lh[dst[i] >> BSHIFT], 1);
    }
    __syncthreads();
    for (int i = threadIdx.x; i < B; i += blockDim.x) {
        int c = lh[i];
        if (c) atomicAdd(&hist[i], c);
    }
}

// ---------- phase 1b: exclusive scan (single block, B <= 1024) ----------
__global__ void scan_kernel(const int* __restrict__ hist, int* __restrict__ bucket_start,
                            int* __restrict__ cursor, int B) {
    __shared__ int lds[MAXB];
    int tid = threadIdx.x;
    int v = (tid < B) ? hist[tid] : 0;
    lds[tid] = v;
    __syncthreads();
    for (int off = 1; off < MAXB; off <<= 1) {
        int t = (tid >= off) ? lds[tid - off] : 0;
        __syncthreads();
        lds[tid] += t;
        __syncthreads();
    }
    if (tid < B) {
        int excl = lds[tid] - v;
        bucket_start[tid] = excl;
        cursor[tid] = excl;
        if (tid == B - 1) bucket_start[B] = lds[tid];
    }
}

// ---------- phase 1c: block-chunked scatter into buckets ----------
// One block per TILE_E-edge tile: count per bucket in LDS, reserve one global
// chunk per (tile,bucket), place packed edges: src | (local_dst << 17).
__global__ void scatter_pass_kernel(const int* __restrict__ src, const int* __restrict__ dst,
                                    int* __restrict__ cursor, unsigned* __restrict__ packed,
                                    int E, int B) {
    __shared__ int lcount[MAXB];
    __shared__ int lbase[MAXB];
    int tid = threadIdx.x;
    int base = blockIdx.x * TILE_E;
    int nE = min(TILE_E, E - base);          // edges in this tile

    for (int i = tid; i < B; i += SP_BLOCK) lcount[i] = 0;
    __syncthreads();

    // pass 1: count (int4 where aligned)
    int n4 = nE >> 2;
    const int4* dst4 = (const int4*)(dst + base);
    for (int k = tid; k < n4; k += SP_BLOCK) {
        int4 d = dst4[k];
        atomicAdd(&lcount[d.x >> BSHIFT], 1);
        atomicAdd(&lcount[d.y >> BSHIFT], 1);
        atomicAdd(&lcount[d.z >> BSHIFT], 1);
        atomicAdd(&lcount[d.w >> BSHIFT], 1);
    }
    for (int i = (n4 << 2) + tid; i < nE; i += SP_BLOCK)
        atomicAdd(&lcount[dst[base + i] >> BSHIFT], 1);
    __syncthreads();

    // reserve global chunks, reset counters
    for (int b = tid; b < B; b += SP_BLOCK) {
        int c = lcount[b];
        lbase[b] = c ? atomicAdd(&cursor[b], c) : 0;
        lcount[b] = 0;
    }
    __syncthreads();

    // pass 2: place
    for (int i = tid; i < nE; i += SP_BLOCK) {
        int d = dst[base + i];
        int b = d >> BSHIFT;
        int pos = lbase[b] + atomicAdd(&lcount[b], 1);
        packed[pos] = (unsigned)src[base + i] | ((unsigned)(d & (NPB - 1)) << 17);
    }
}

// ---------- phase 2: per-bucket scatter-max in LDS ----------
// 8 waves/block. Each wave lane-loads 64 packed edges (one coalesced 256B
// load), broadcasts each via __shfl, and issues 4 independent h-row loads
// per unrolled group for MLP.
__global__ void __launch_bounds__(BM_BLOCK)
bucket_max_kernel(const float* __restrict__ h,
                  const int* __restrict__ bucket_start,
                  const unsigned* __restrict__ packed,
                  float* __restrict__ out, int N) {
    __shared__ unsigned buf[NPB * D_FEAT];   // 32 KB
    int b = blockIdx.x;
    int tid = threadIdx.x;
    int node0 = b << BSHIFT;
    int nvals = (min(NPB, N - node0)) * D_FEAT;

    for (int i = tid; i < NPB * D_FEAT; i += BM_BLOCK) buf[i] = ENC_NEG_INF;
    __syncthreads();

    int beg = bucket_start[b];
    int end = bucket_start[b + 1];
    int wid = tid >> 6;
    int lane = tid & 63;

    for (int base = beg + (wid << 6); base < end; base += BM_BLOCK) {
        int nk = min(64, end - base);
        unsigned p = (lane < nk) ? packed[base + lane] : 0u;
        int j = 0;
        for (; j + 4 <= nk; j += 4) {
            unsigned p0 = (unsigned)__shfl((int)p, j);
            unsigned p1 = (unsigned)__shfl((int)p, j + 1);
            unsigned p2 = (unsigned)__shfl((int)p, j + 2);
            unsigned p3 = (unsigned)__shfl((int)p, j + 3);
            float v0 = h[(p0 & 0x1FFFFu) * D_FEAT + lane];
            float v1 = h[(p1 & 0x1FFFFu) * D_FEAT + lane];
            float v2 = h[(p2 & 0x1FFFFu) * D_FEAT + lane];
            float v3 = h[(p3 & 0x1FFFFu) * D_FEAT + lane];
            atomicMax(&buf[(p0 >> 17) * D_FEAT + lane], enc_f32(v0));
            atomicMax(&buf[(p1 >> 17) * D_FEAT + lane], enc_f32(v1));
            atomicMax(&buf[(p2 >> 17) * D_FEAT + lane], enc_f32(v2));
            atomicMax(&buf[(p3 >> 17) * D_FEAT + lane], enc_f32(v3));
        }
        for (; j < nk; ++j) {
            unsigned pj = (unsigned)__shfl((int)p, j);
            float v = h[(pj & 0x1FFFFu) * D_FEAT + lane];
            atomicMax(&buf[(pj >> 17) * D_FEAT + lane], enc_f32(v));
        }
    }
    __syncthreads();

    for (int i = tid; i < nvals; i += BM_BLOCK) {
        unsigned u = buf[i];
        out[node0 * D_FEAT + i] = (u == ENC_NEG_INF) ? 0.0f : dec_f32(u);
    }
}

// ---------- fallback: atomic scatter (round-1 path) ----------
__global__ void init_out_kernel(uint4* __restrict__ out, int n4) {
    int i = blockIdx.x * blockDim.x + threadIdx.x;
    if (i < n4) {
        uint4 v;
        v.x = NEG_INF_BITS; v.y = NEG_INF_BITS; v.z = NEG_INF_BITS; v.w = NEG_INF_BITS;
        out[i] = v;
    }
}
__global__ void scatter_max_kernel(const float* __restrict__ h, const int* __restrict__ src,
                                   const int* __restrict__ dst, float* __restrict__ out, int E) {
    int gid = blockIdx.x * blockDim.x + threadIdx.x;
    int e = gid >> 6;
    if (e >= E) return;
    int lane = gid & 63;
    float v = h[src[e] * D_FEAT + lane];
    int* addr = (int*)(out + dst[e] * D_FEAT + lane);
    if (v >= 0.0f) atomicMax(addr, __float_as_int(v));
    else           atomicMin((unsigned int*)addr, __float_as_uint(v));
}
__global__ void finalize_kernel(float* __restrict__ out, int n) {
    int i = blockIdx.x * blockDim.x + threadIdx.x;
    if (i < n && __float_as_uint(out[i]) == NEG_INF_BITS) out[i] = 0.0f;
}

// ---------- launch ----------
extern "C" void kernel_launch(void* const* d_in, const int* in_sizes, int n_in,
                              void* d_out, int out_size, void* d_ws, size_t ws_size,
                              hipStream_t stream) {
    const float* h = (const float*)d_in[0];
    const int* edge_index = (const int*)d_in[1];
    int E = in_sizes[1] / 2;                 // edge_index is [2, E] row-major
    const int* src = edge_index;
    const int* dst = edge_index + E;
    float* out = (float*)d_out;
    int N = out_size / D_FEAT;

    int B = (N + NPB - 1) >> BSHIFT;
    size_t ws_needed = (size_t)(3 * B + 2 + E) * sizeof(int);

    if (N <= (1 << 17) && B <= MAXB && ws_size >= ws_needed) {
        int* hist         = (int*)d_ws;              // [B]
        int* bucket_start = hist + B;                // [B+1]
        int* cursor       = bucket_start + B + 1;    // [B]
        unsigned* packed  = (unsigned*)(cursor + B); // [E]

        zero_kernel<<<(B + 255) / 256, 256, 0, stream>>>(hist, B);
        hist_kernel<<<512, 256, 0, stream>>>(dst, hist, E, B);
        scan_kernel<<<1, MAXB, 0, stream>>>(hist, bucket_start, cursor, B);
        int ntiles = (E + TILE_E - 1) / TILE_E;
        scatter_pass_kernel<<<ntiles, SP_BLOCK, 0, stream>>>(src, dst, cursor, packed, E, B);
        bucket_max_kernel<<<B, BM_BLOCK, 0, stream>>>(h, bucket_start, packed, out, N);
    } else {
        int n4 = out_size / 4;
        init_out_kernel<<<(n4 + 255) / 256, 256, 0, stream>>>((uint4*)out, n4);
        long long total = (long long)E * 64;
        scatter_max_kernel<<<(int)((total + 255) / 256), 256, 0, stream>>>(h, src, dst, out, E);
        finalize_kernel<<<(out_size + 255) / 256, 256, 0, stream>>>(out, out_size);
    }
}

// Round 5
// 163.540 us; speedup vs baseline: 2.6269x; 1.0890x over previous
//
#include <hip/hip_runtime.h>

#define D_FEAT 64
#define NEG_INF_BITS 0xFF800000u
#define ENC_NEG_INF  0x007FFFFFu   // order-preserving encoding of -inf
#define NPB 128                     // nodes per bucket (= 1 << BSHIFT)
#define BSHIFT 7
#define BM_BLOCK 512                // bucket_max threads (8 waves)
#define MAXB 1024                   // max buckets

// Order-preserving float->uint: enc monotone increasing with float value.
__device__ __forceinline__ unsigned enc_f32(float v) {
    unsigned b = __float_as_uint(v);
    return ((int)b >= 0) ? (b ^ 0x80000000u) : ~b;
}
__device__ __forceinline__ float dec_f32(unsigned u) {
    return (u & 0x80000000u) ? __uint_as_float(u ^ 0x80000000u) : __uint_as_float(~u);
}

// ---------- K1: per-tile bucket histogram (LDS only, deterministic output) ----------
__global__ void count_kernel(const int* __restrict__ dst, int* __restrict__ counts,
                             int E, int Te, int B) {
    __shared__ int lh[MAXB];
    for (int i = threadIdx.x; i < B; i += blockDim.x) lh[i] = 0;
    __syncthreads();
    int t = blockIdx.x;
    int beg = t * Te;
    int end = min(E, beg + Te);
    int nE = (end > beg) ? (end - beg) : 0;
    int n4 = nE >> 2;
    const int4* d4 = (const int4*)(dst + beg);   // beg is a multiple of 4
    for (int k = threadIdx.x; k < n4; k += blockDim.x) {
        int4 d = d4[k];
        atomicAdd(&lh[d.x >> BSHIFT], 1);
        atomicAdd(&lh[d.y >> BSHIFT], 1);
        atomicAdd(&lh[d.z >> BSHIFT], 1);
        atomicAdd(&lh[d.w >> BSHIFT], 1);
    }
    for (int i = beg + (n4 << 2) + threadIdx.x; i < end; i += blockDim.x)
        atomicAdd(&lh[dst[i] >> BSHIFT], 1);
    __syncthreads();
    for (int i = threadIdx.x; i < B; i += blockDim.x) counts[t * B + i] = lh[i];
}

// ---------- K2a: per-bucket column exclusive scan over tiles (in place) ----------
// One wave per bucket. Lane j holds tiles t = j*R .. j*R+R-1 (R = T/64).
// counts[t][b] <- sum_{t'<t} counts[t'][b]; hist[b] <- column total.
__global__ void colscan_kernel(int* __restrict__ counts, int* __restrict__ hist,
                               int T, int B) {
    int w = (blockIdx.x * blockDim.x + threadIdx.x) >> 6;
    int lane = threadIdx.x & 63;
    if (w >= B) return;
    int b = w;
    int R = T >> 6;                       // 1, 2, or 4
    int v[4], pre[4];
    int base_t = lane * R;
    for (int r = 0; r < R; ++r) v[r] = counts[(base_t + r) * B + b];
    int s = 0;
    for (int r = 0; r < R; ++r) { pre[r] = s; s += v[r]; }
    int incl = s;
    for (int off = 1; off < 64; off <<= 1) {
        int tup = __shfl_up(incl, off);
        if (lane >= off) incl += tup;
    }
    int excl = incl - s;
    for (int r = 0; r < R; ++r) counts[(base_t + r) * B + b] = excl + pre[r];
    int total = __shfl(incl, 63);
    if (lane == 0) hist[b] = total;
}

// ---------- K2b: single-block exclusive scan of bucket totals ----------
__global__ void scan_kernel(const int* __restrict__ hist, int* __restrict__ bucket_start,
                            int B) {
    __shared__ int lds[MAXB];
    int tid = threadIdx.x;
    int v = (tid < B) ? hist[tid] : 0;
    lds[tid] = v;
    __syncthreads();
    for (int off = 1; off < MAXB; off <<= 1) {
        int t = (tid >= off) ? lds[tid - off] : 0;
        __syncthreads();
        lds[tid] += t;
        __syncthreads();
    }
    if (tid < B) {
        bucket_start[tid] = lds[tid] - v;
        if (tid == B - 1) bucket_start[B] = lds[tid];
    }
}

// ---------- K3: place edges (LDS cursor from precomputed offsets; no global atomics) ----------
__global__ void place_kernel(const int* __restrict__ src, const int* __restrict__ dst,
                             const int* __restrict__ counts, const int* __restrict__ bucket_start,
                             unsigned* __restrict__ packed, int E, int Te, int B) {
    __shared__ int lcur[MAXB];
    int t = blockIdx.x;
    for (int i = threadIdx.x; i < B; i += blockDim.x)
        lcur[i] = bucket_start[i] + counts[t * B + i];
    __syncthreads();
    int beg = t * Te;
    int end = min(E, beg + Te);
    for (int i = beg + threadIdx.x; i < end; i += blockDim.x) {
        int d = dst[i];
        int b = d >> BSHIFT;
        int pos = atomicAdd(&lcur[b], 1);
        packed[pos] = (unsigned)src[i] | ((unsigned)(d & (NPB - 1)) << 17);
    }
}

// ---------- K4: per-bucket scatter-max in LDS ----------
__global__ void __launch_bounds__(BM_BLOCK)
bucket_max_kernel(const float* __restrict__ h,
                  const int* __restrict__ bucket_start,
                  const unsigned* __restrict__ packed,
                  float* __restrict__ out, int N) {
    __shared__ unsigned buf[NPB * D_FEAT];   // 32 KB
    int b = blockIdx.x;
    int tid = threadIdx.x;
    int node0 = b << BSHIFT;
    int nvals = (min(NPB, N - node0)) * D_FEAT;

    for (int i = tid; i < NPB * D_FEAT; i += BM_BLOCK) buf[i] = ENC_NEG_INF;
    __syncthreads();

    int beg = bucket_start[b];
    int end = bucket_start[b + 1];
    int wid = tid >> 6;
    int lane = tid & 63;

    for (int base = beg + (wid << 6); base < end; base += BM_BLOCK) {
        int nk = min(64, end - base);
        unsigned p = (lane < nk) ? packed[base + lane] : 0u;
        int j = 0;
        for (; j + 8 <= nk; j += 8) {
            unsigned q[8];
            float v[8];
            #pragma unroll
            for (int k = 0; k < 8; ++k) q[k] = (unsigned)__shfl((int)p, j + k);
            #pragma unroll
            for (int k = 0; k < 8; ++k) v[k] = h[(q[k] & 0x1FFFFu) * D_FEAT + lane];
            #pragma unroll
            for (int k = 0; k < 8; ++k)
                atomicMax(&buf[(q[k] >> 17) * D_FEAT + lane], enc_f32(v[k]));
        }
        for (; j < nk; ++j) {
            unsigned pj = (unsigned)__shfl((int)p, j);
            float v = h[(pj & 0x1FFFFu) * D_FEAT + lane];
            atomicMax(&buf[(pj >> 17) * D_FEAT + lane], enc_f32(v));
        }
    }
    __syncthreads();

    for (int i = tid; i < nvals; i += BM_BLOCK) {
        unsigned u = buf[i];
        out[node0 * D_FEAT + i] = (u == ENC_NEG_INF) ? 0.0f : dec_f32(u);
    }
}

// ---------- fallback: atomic scatter (round-1 path) ----------
__global__ void init_out_kernel(uint4* __restrict__ out, int n4) {
    int i = blockIdx.x * blockDim.x + threadIdx.x;
    if (i < n4) {
        uint4 v;
        v.x = NEG_INF_BITS; v.y = NEG_INF_BITS; v.z = NEG_INF_BITS; v.w = NEG_INF_BITS;
        out[i] = v;
    }
}
__global__ void scatter_max_kernel(const float* __restrict__ h, const int* __restrict__ src,
                                   const int* __restrict__ dst, float* __restrict__ out, int E) {
    int gid = blockIdx.x * blockDim.x + threadIdx.x;
    int e = gid >> 6;
    if (e >= E) return;
    int lane = gid & 63;
    float v = h[src[e] * D_FEAT + lane];
    int* addr = (int*)(out + dst[e] * D_FEAT + lane);
    if (v >= 0.0f) atomicMax(addr, __float_as_int(v));
    else           atomicMin((unsigned int*)addr, __float_as_uint(v));
}
__global__ void finalize_kernel(float* __restrict__ out, int n) {
    int i = blockIdx.x * blockDim.x + threadIdx.x;
    if (i < n && __float_as_uint(out[i]) == NEG_INF_BITS) out[i] = 0.0f;
}

// ---------- launch ----------
extern "C" void kernel_launch(void* const* d_in, const int* in_sizes, int n_in,
                              void* d_out, int out_size, void* d_ws, size_t ws_size,
                              hipStream_t stream) {
    const float* h = (const float*)d_in[0];
    const int* edge_index = (const int*)d_in[1];
    int E = in_sizes[1] / 2;                 // edge_index is [2, E] row-major
    const int* src = edge_index;
    const int* dst = edge_index + E;
    float* out = (float*)d_out;
    int N = out_size / D_FEAT;

    int B = (N + NPB - 1) >> BSHIFT;

    // pick the largest tile count T whose workspace fits
    int T = 0;
    for (int cand = 256; cand >= 64; cand >>= 1) {
        size_t need = ((size_t)cand * B + B + (B + 1) + (size_t)E) * sizeof(int);
        if (ws_size >= need) { T = cand; break; }
    }

    if (N <= (1 << 17) && B <= MAXB && T > 0) {
        int* counts       = (int*)d_ws;                 // [T*B]
        int* hist         = counts + (size_t)T * B;     // [B]
        int* bucket_start = hist + B;                   // [B+1]
        unsigned* packed  = (unsigned*)(bucket_start + B + 1); // [E]

        int Te = ((E + T - 1) / T + 3) & ~3;            // tile size, multiple of 4

        count_kernel<<<T, 512, 0, stream>>>(dst, counts, E, Te, B);
        int cs_blocks = (B * 64 + 511) / 512;
        colscan_kernel<<<cs_blocks, 512, 0, stream>>>(counts, hist, T, B);
        scan_kernel<<<1, MAXB, 0, stream>>>(hist, bucket_start, B);
        place_kernel<<<T, 512, 0, stream>>>(src, dst, counts, bucket_start, packed, E, Te, B);
        bucket_max_kernel<<<B, BM_BLOCK, 0, stream>>>(h, bucket_start, packed, out, N);
    } else {
        int n4 = out_size / 4;
        init_out_kernel<<<(n4 + 255) / 256, 256, 0, stream>>>((uint4*)out, n4);
        long long total = (long long)E * 64;
        scatter_max_kernel<<<(int)((total + 255) / 256), 256, 0, stream>>>(h, src, dst, out, E);
        finalize_kernel<<<(out_size + 255) / 256, 256, 0, stream>>>(out, out_size);
    }
}